// Round 1
// baseline (428.803 us; speedup 1.0000x reference)
//
#include <hip/hip_runtime.h>
#include <math.h>

#define BATCH 64
#define NN 512
#define DD 128
#define SLOPE 0.2f
#define NEG_BIG -3.0e38f

// ---------------------------------------------------------------------------
// Kernel 1: thresh[b] = ||sum_n E[b,n,:]||^2 / N^2   (exact identity for
// mean_{i,j} E_i . E_j)
// ---------------------------------------------------------------------------
__global__ __launch_bounds__(1024) void k_thresh(const float* __restrict__ E,
                                                 float* __restrict__ thresh) {
    int b = blockIdx.x;
    int t = threadIdx.x;
    int d = t & 127;
    int seg = t >> 7;  // 8 segments of 64 rows
    const float* Eb = E + (size_t)b * NN * DD;
    float s = 0.f;
    int n0 = seg * 64;
    #pragma unroll 8
    for (int n = 0; n < 64; ++n) s += Eb[(size_t)(n0 + n) * DD + d];
    __shared__ float red[8][128];
    red[seg][d] = s;
    __syncthreads();
    __shared__ float r2[128];
    if (t < 128) {
        float tot = 0.f;
        #pragma unroll
        for (int g = 0; g < 8; ++g) tot += red[g][t];
        r2[t] = tot * tot;
    }
    __syncthreads();
    for (int off = 64; off > 0; off >>= 1) {
        if (t < off) r2[t] += r2[t + off];
        __syncthreads();
    }
    if (t == 0) thresh[b] = r2[0] * (1.0f / ((float)NN * (float)NN));
}

// ---------------------------------------------------------------------------
// Kernel 2: z = E @ W  [B,N,128]; el = z @ attn_l; er = z @ attn_r
// One block = 8 nodes x 128 outputs. W reads are coalesced + L2-resident.
// ---------------------------------------------------------------------------
__global__ __launch_bounds__(128) void k_z(const float* __restrict__ E,
                                           const float* __restrict__ W,
                                           const float* __restrict__ al,
                                           const float* __restrict__ ar,
                                           float* __restrict__ z,
                                           float* __restrict__ el,
                                           float* __restrict__ er) {
    int b = blockIdx.y;
    int n0 = blockIdx.x * 8;
    int d = threadIdx.x;
    const float* Eb = E + ((size_t)b * NN + n0) * DD;

    __shared__ float e_t[8][DD];
    #pragma unroll
    for (int r = 0; r < 8; ++r) e_t[r][d] = Eb[(size_t)r * DD + d];
    __syncthreads();

    float acc[8];
    #pragma unroll
    for (int r = 0; r < 8; ++r) acc[r] = 0.f;

    #pragma unroll 4
    for (int k = 0; k < DD; ++k) {
        float w = W[(size_t)k * DD + d];
        #pragma unroll
        for (int r = 0; r < 8; ++r) acc[r] += e_t[r][k] * w;
    }

    float* zb = z + ((size_t)b * NN + n0) * DD;
    #pragma unroll
    for (int r = 0; r < 8; ++r) zb[(size_t)r * DD + d] = acc[r];

    // el/er: 8 dot-products of acc with attn vectors, wave-shuffle reduce
    float a_l = al[d], a_r = ar[d];
    __shared__ float wl[2][8], wr[2][8];
    #pragma unroll
    for (int r = 0; r < 8; ++r) {
        float vl = acc[r] * a_l;
        float vr = acc[r] * a_r;
        for (int off = 32; off > 0; off >>= 1) {
            vl += __shfl_down(vl, off);
            vr += __shfl_down(vr, off);
        }
        if ((d & 63) == 0) {
            wl[d >> 6][r] = vl;
            wr[d >> 6][r] = vr;
        }
    }
    __syncthreads();
    if (d < 8) el[b * NN + n0 + d] = wl[0][d] + wl[1][d];
    else if (d < 16) er[b * NN + n0 + d - 8] = wr[0][d - 8] + wr[1][d - 8];
}

// ---------------------------------------------------------------------------
// Kernel 3: main flash-style masked attention + elu + mean pool.
// Block = (b, 32-wide j tile), 256 threads. Loop over 8 chunks of 64 src i.
// ---------------------------------------------------------------------------
__global__ __launch_bounds__(256) void k_main(const float* __restrict__ E,
                                              const float* __restrict__ z,
                                              const float* __restrict__ el,
                                              const float* __restrict__ er,
                                              const float* __restrict__ thresh,
                                              const float* __restrict__ bias,
                                              float* __restrict__ out) {
    int b = blockIdx.y;
    int j0 = blockIdx.x * 32;
    int t = threadIdx.x;
    const float* Eb = E + (size_t)b * NN * DD;
    const float* zb = z + (size_t)b * NN * DD;

    __shared__ float Ej[32][132];   // padded: conflict-free f4 reads
    __shared__ float Ei[64][132];
    __shared__ float p[64][33];     // scores -> masked logits -> exp weights
    __shared__ float el_c[64], er_t[32];
    __shared__ float m_s[32], Z_s[32], scale_s[32];
    __shared__ float lred[8][32];
    __shared__ float thr_s;

    for (int idx = t; idx < 32 * DD; idx += 256) {
        int r = idx >> 7, c = idx & 127;
        Ej[r][c] = Eb[(size_t)(j0 + r) * DD + c];
    }
    if (t < 32) { er_t[t] = er[b * NN + j0 + t]; m_s[t] = NEG_BIG; Z_s[t] = 0.f; }
    if (t == 0) thr_s = thresh[b];

    float h[16];
    #pragma unroll
    for (int q = 0; q < 16; ++q) h[q] = 0.f;

    int jo = t & 31;       // owned dst column (softmax/agg phases)
    int grp = t >> 5;      // 0..7
    int d0 = grp * 16;     // owned d-range for h
    int ii = t & 63;       // owned src row (score phase)
    int jg = t >> 6;       // 0..3 -> 8 j's each (score phase)

    __syncthreads();

    for (int i0 = 0; i0 < NN; i0 += 64) {
        // ---- stage Ei chunk + el chunk
        for (int idx = t; idx < 64 * DD; idx += 256) {
            int r = idx >> 7, c = idx & 127;
            Ei[r][c] = Eb[(size_t)(i0 + r) * DD + c];
        }
        if (t < 64) el_c[t] = el[b * NN + i0 + t];
        __syncthreads();  // (A)

        // ---- scores S[ii][jg*8..+7] = Ei . Ej
        float acc[8];
        #pragma unroll
        for (int u = 0; u < 8; ++u) acc[u] = 0.f;
        for (int k = 0; k < DD; k += 4) {
            float4 a = *(const float4*)&Ei[ii][k];
            #pragma unroll
            for (int u = 0; u < 8; ++u) {
                float4 bb = *(const float4*)&Ej[jg * 8 + u][k];
                acc[u] += a.x * bb.x + a.y * bb.y + a.z * bb.z + a.w * bb.w;
            }
        }
        // ---- masked leaky-relu logits -> p
        {
            float thr = thr_s;
            float eli = el_c[ii];
            int gi = i0 + ii;
            #pragma unroll
            for (int u = 0; u < 8; ++u) {
                int j = jg * 8 + u;
                float x = eli + er_t[j];
                float lg = x > 0.f ? x : SLOPE * x;
                bool keep = (acc[u] > thr) || (gi == j0 + j);
                p[ii][j] = keep ? lg : NEG_BIG;
            }
        }
        __syncthreads();  // (B)

        // ---- step1: per-column local max over 8 ii's
        {
            float lm = NEG_BIG;
            #pragma unroll
            for (int v = 0; v < 8; ++v) lm = fmaxf(lm, p[grp * 8 + v][jo]);
            lred[grp][jo] = lm;
        }
        __syncthreads();  // (C)

        // ---- step2: new max + rescale factor
        if (t < 32) {
            float nm = m_s[t];
            #pragma unroll
            for (int g = 0; g < 8; ++g) nm = fmaxf(nm, lred[g][t]);
            float sc = __expf(m_s[t] - nm);  // both NEG_BIG -> exp(0)=1, Z=0 anyway
            m_s[t] = nm;
            scale_s[t] = sc;
        }
        __syncthreads();  // (D)

        // ---- step3: exponentiate (guard masked sentinel), local sums
        {
            float mj = m_s[jo];
            float ls = 0.f;
            #pragma unroll
            for (int v = 0; v < 8; ++v) {
                float pv = p[grp * 8 + v][jo];
                float pe = (pv < -1.0e37f) ? 0.f : __expf(pv - mj);
                p[grp * 8 + v][jo] = pe;
                ls += pe;
            }
            lred[grp][jo] = ls;
        }
        __syncthreads();  // (E)

        // ---- step4: Z update
        if (t < 32) {
            float s = 0.f;
            #pragma unroll
            for (int g = 0; g < 8; ++g) s += lred[g][t];
            Z_s[t] = Z_s[t] * scale_s[t] + s;
        }

        // ---- step5: h[jo][d0..d0+15] = h*scale + sum_ii p[ii][jo]*z[i0+ii][d]
        {
            float sc = scale_s[jo];
            #pragma unroll
            for (int q = 0; q < 16; ++q) h[q] *= sc;
            for (int iq = 0; iq < 64; ++iq) {
                float w = p[iq][jo];
                const float* zr = zb + (size_t)(i0 + iq) * DD + d0;
                float4 z0 = *(const float4*)&zr[0];
                float4 z1 = *(const float4*)&zr[4];
                float4 z2 = *(const float4*)&zr[8];
                float4 z3 = *(const float4*)&zr[12];
                h[0]  += w * z0.x; h[1]  += w * z0.y; h[2]  += w * z0.z; h[3]  += w * z0.w;
                h[4]  += w * z1.x; h[5]  += w * z1.y; h[6]  += w * z1.z; h[7]  += w * z1.w;
                h[8]  += w * z2.x; h[9]  += w * z2.y; h[10] += w * z2.z; h[11] += w * z2.w;
                h[12] += w * z3.x; h[13] += w * z3.y; h[14] += w * z3.z; h[15] += w * z3.w;
            }
        }
        __syncthreads();  // re-converge before next staging overwrites Ei/p
    }

    // ---- epilogue: normalize, +bias, elu, mean over j, atomic accumulate
    float Zinv = 1.0f / Z_s[jo];
    float* red = &Ei[0][0];  // reuse as [32][132]
    #pragma unroll
    for (int q = 0; q < 16; ++q) {
        float v = h[q] * Zinv + bias[d0 + q];
        v = v > 0.f ? v : (__expf(v) - 1.f);
        red[jo * 132 + d0 + q] = v;
    }
    __syncthreads();
    if (t < 128) {
        float s = 0.f;
        #pragma unroll
        for (int j = 0; j < 32; ++j) s += red[j * 132 + t];
        atomicAdd(&out[b * DD + t], s * (1.0f / NN));
    }
}

// ---------------------------------------------------------------------------
extern "C" void kernel_launch(void* const* d_in, const int* in_sizes, int n_in,
                              void* d_out, int out_size, void* d_ws, size_t ws_size,
                              hipStream_t stream) {
    const float* E    = (const float*)d_in[0];
    const float* W    = (const float*)d_in[1];
    const float* al   = (const float*)d_in[2];
    const float* ar   = (const float*)d_in[3];
    const float* bias = (const float*)d_in[4];
    float* out = (float*)d_out;

    float* z   = (float*)d_ws;                       // B*N*D floats = 16 MB
    float* el  = z + (size_t)BATCH * NN * DD;        // B*N
    float* er  = el + (size_t)BATCH * NN;            // B*N
    float* thr = er + (size_t)BATCH * NN;            // B

    hipMemsetAsync(d_out, 0, sizeof(float) * (size_t)out_size, stream);

    k_thresh<<<dim3(BATCH), dim3(1024), 0, stream>>>(E, thr);
    k_z<<<dim3(NN / 8, BATCH), dim3(128), 0, stream>>>(E, W, al, ar, z, el, er);
    k_main<<<dim3(NN / 32, BATCH), dim3(256), 0, stream>>>(E, z, el, er, thr, bias, out);
}

// Round 2
// 163.237 us; speedup vs baseline: 2.6269x; 2.6269x over previous
//
#include <hip/hip_runtime.h>
#include <math.h>

#define BATCH 64
#define NN 512
#define DD 128
#define SLOPE 0.2f
#define NEG_BIG -3.0e38f

typedef unsigned short u16;
typedef short bf16x8 __attribute__((ext_vector_type(8)));
typedef u16 u16x4 __attribute__((ext_vector_type(4)));
typedef u16 u16x8 __attribute__((ext_vector_type(8)));
typedef float f32x4 __attribute__((ext_vector_type(4)));

static __device__ __forceinline__ u16 f2bf(float x) {
    unsigned int u = __float_as_uint(x);
    unsigned int r = (u + 0x7fffu + ((u >> 16) & 1u)) >> 16;
    return (u16)r;
}
static __device__ __forceinline__ float bf2f(u16 h) {
    return __uint_as_float(((unsigned int)h) << 16);
}

// ---------------------------------------------------------------------------
// Kernel 1: thresh[b] = ||sum_n E[b,n,:]||^2 / N^2  (exact identity)
// ---------------------------------------------------------------------------
__global__ __launch_bounds__(1024) void k_thresh(const float* __restrict__ E,
                                                 float* __restrict__ thresh) {
    int b = blockIdx.x;
    int t = threadIdx.x;
    int d = t & 127;
    int seg = t >> 7;
    const float* Eb = E + (size_t)b * NN * DD;
    float s = 0.f;
    int n0 = seg * 64;
    #pragma unroll 8
    for (int n = 0; n < 64; ++n) s += Eb[(size_t)(n0 + n) * DD + d];
    __shared__ float red[8][128];
    red[seg][d] = s;
    __syncthreads();
    __shared__ float r2[128];
    if (t < 128) {
        float tot = 0.f;
        #pragma unroll
        for (int g = 0; g < 8; ++g) tot += red[g][t];
        r2[t] = tot * tot;
    }
    __syncthreads();
    for (int off = 64; off > 0; off >>= 1) {
        if (t < off) r2[t] += r2[t + off];
        __syncthreads();
    }
    if (t == 0) thresh[b] = r2[0] * (1.0f / ((float)NN * (float)NN));
}

// ---------------------------------------------------------------------------
// Kernel 2: z = E@W; emit Ebf (bf16 E, row-major), zT (bf16 z^T [B][D][N]),
// el = z@attn_l, er = z@attn_r.
// ---------------------------------------------------------------------------
__global__ __launch_bounds__(128) void k_z(const float* __restrict__ E,
                                           const float* __restrict__ W,
                                           const float* __restrict__ al,
                                           const float* __restrict__ ar,
                                           u16* __restrict__ Ebf,
                                           u16* __restrict__ zT,
                                           float* __restrict__ el,
                                           float* __restrict__ er) {
    int b = blockIdx.y;
    int n0 = blockIdx.x * 8;
    int d = threadIdx.x;
    const float* Eb = E + ((size_t)b * NN + n0) * DD;

    __shared__ float e_t[8][DD];
    #pragma unroll
    for (int r = 0; r < 8; ++r) {
        float v = Eb[(size_t)r * DD + d];
        e_t[r][d] = v;
        Ebf[((size_t)b * NN + n0 + r) * DD + d] = f2bf(v);
    }
    __syncthreads();

    float acc[8];
    #pragma unroll
    for (int r = 0; r < 8; ++r) acc[r] = 0.f;

    #pragma unroll 4
    for (int k = 0; k < DD; ++k) {
        float w = W[(size_t)k * DD + d];
        #pragma unroll
        for (int r = 0; r < 8; ++r) acc[r] += e_t[r][k] * w;
    }

    // zT[b][d][n0..n0+7] as one 16B store
    u16x8 pk;
    #pragma unroll
    for (int r = 0; r < 8; ++r) pk[r] = f2bf(acc[r]);
    *(u16x8*)&zT[((size_t)b * DD + d) * NN + n0] = pk;

    // el/er dot products
    float a_l = al[d], a_r = ar[d];
    __shared__ float wl[2][8], wr[2][8];
    #pragma unroll
    for (int r = 0; r < 8; ++r) {
        float vl = acc[r] * a_l;
        float vr = acc[r] * a_r;
        for (int off = 32; off > 0; off >>= 1) {
            vl += __shfl_down(vl, off);
            vr += __shfl_down(vr, off);
        }
        if ((d & 63) == 0) {
            wl[d >> 6][r] = vl;
            wr[d >> 6][r] = vr;
        }
    }
    __syncthreads();
    if (d < 8) el[b * NN + n0 + d] = wl[0][d] + wl[1][d];
    else if (d < 16) er[b * NN + n0 + d - 8] = wr[0][d - 8] + wr[1][d - 8];
}

// ---------------------------------------------------------------------------
// Kernel 3: flash-style masked GAT attention via bf16 MFMA.
// Block = (b, 32 dst-cols), 256 threads = 4 waves. Chunks of 64 src rows.
// Phase A: S = Ei . Ej^T (MFMA, frags direct from global Ebf).
// Phase B: H += P^T . z   (P through LDS C->A layout, zT frags from global).
// ---------------------------------------------------------------------------
__global__ __launch_bounds__(256) void k_main(const u16* __restrict__ Ebf,
                                              const u16* __restrict__ zT,
                                              const float* __restrict__ el,
                                              const float* __restrict__ er,
                                              const float* __restrict__ thresh,
                                              const float* __restrict__ bias,
                                              float* __restrict__ out) {
    int b = blockIdx.y;
    int j0 = blockIdx.x * 32;
    int t = threadIdx.x;
    int w = t >> 6;
    int lane = t & 63;
    int l15 = lane & 15;
    int quad = lane >> 4;
    int mtile = w & 1;        // phase-B j-tile owned by this wave
    int ngrp = (w >> 1) * 4;  // phase-B d-tile group base (4 tiles of 16)

    const u16* Eb = Ebf + (size_t)b * NN * DD;
    const u16* zTb = zT + (size_t)b * DD * NN;

    __shared__ u16 pT[32][72];      // P^T bf16, padded (+8 -> 144B row stride)
    __shared__ float red[16][33];
    __shared__ float m_s[32], scale_s[32], Zs[32];
    __shared__ float osum[128];

    // persistent Ej B-frags: B[n=j][k=d]
    bf16x8 bEj[2][4];
    #pragma unroll
    for (int jt = 0; jt < 2; ++jt)
        #pragma unroll
        for (int ks = 0; ks < 4; ++ks)
            bEj[jt][ks] = *(const bf16x8*)(Eb + (size_t)(j0 + jt * 16 + l15) * DD + ks * 32 + quad * 8);

    float thr = thresh[b];
    float er_v[2] = { er[b * NN + j0 + l15], er[b * NN + j0 + 16 + l15] };

    f32x4 H[4];
    #pragma unroll
    for (int nt = 0; nt < 4; ++nt) H[nt] = (f32x4){0.f, 0.f, 0.f, 0.f};
    float zpart[2] = {0.f, 0.f};
    if (t < 32) m_s[t] = NEG_BIG;
    if (t < 128) osum[t] = 0.f;

    for (int i0 = 0; i0 < NN; i0 += 64) {
        int ib = i0 + w * 16;  // this wave's phase-A i-block

        // A-frags for scores: Ei[m=i][k=d]
        bf16x8 aE[4];
        #pragma unroll
        for (int ks = 0; ks < 4; ++ks)
            aE[ks] = *(const bf16x8*)(Eb + (size_t)(ib + l15) * DD + ks * 32 + quad * 8);

        // prefetch zT B-frags for phase B: B[k=i][n=d]
        bf16x8 bz[4][2];
        #pragma unroll
        for (int nt = 0; nt < 4; ++nt)
            #pragma unroll
            for (int ks = 0; ks < 2; ++ks)
                bz[nt][ks] = *(const bf16x8*)(zTb + (size_t)((ngrp + nt) * 16 + l15) * NN + i0 + ks * 32 + quad * 8);

        // scores: S[jt] = Ei . Ej^T (16x16 tiles, K=128)
        f32x4 S[2];
        S[0] = (f32x4){0.f, 0.f, 0.f, 0.f};
        S[1] = (f32x4){0.f, 0.f, 0.f, 0.f};
        #pragma unroll
        for (int ks = 0; ks < 4; ++ks) {
            S[0] = __builtin_amdgcn_mfma_f32_16x16x32_bf16(aE[ks], bEj[0][ks], S[0], 0, 0, 0);
            S[1] = __builtin_amdgcn_mfma_f32_16x16x32_bf16(aE[ks], bEj[1][ks], S[1], 0, 0, 0);
        }

        // logits + mask (C layout: col j = l15(+16jt), row i = quad*4+reg)
        float4 el4 = *(const float4*)(el + b * NN + ib + quad * 4);
        float elv[4] = {el4.x, el4.y, el4.z, el4.w};
        float v[2][4];
        bool keep[2][4];
        float mymax[2] = {NEG_BIG, NEG_BIG};
        #pragma unroll
        for (int jt = 0; jt < 2; ++jt) {
            #pragma unroll
            for (int r = 0; r < 4; ++r) {
                int ig = ib + quad * 4 + r;
                int jg = j0 + jt * 16 + l15;
                float x = elv[r] + er_v[jt];
                float lg = x > 0.f ? x : SLOPE * x;
                bool k_ = (S[jt][r] > thr) || (ig == jg);
                keep[jt][r] = k_;
                v[jt][r] = lg;
                if (k_) mymax[jt] = fmaxf(mymax[jt], lg);
            }
        }
        red[w * 4 + quad][l15] = mymax[0];
        red[w * 4 + quad][16 + l15] = mymax[1];
        __syncthreads();  // B1

        if (t < 32) {
            float m = m_s[t];
            float mn = m;
            #pragma unroll
            for (int g = 0; g < 16; ++g) mn = fmaxf(mn, red[g][t]);
            scale_s[t] = __expf(m - mn);  // -3e38-finite -> exp(-huge)=0; both sentinel -> exp(0)=1 (Z=H=0)
            m_s[t] = mn;
        }
        __syncthreads();  // B2

        // exp, P^T write (bf16), running-Z update, H rescale
        #pragma unroll
        for (int jt = 0; jt < 2; ++jt) {
            float mj = m_s[jt * 16 + l15];
            float scj = scale_s[jt * 16 + l15];
            float ls = 0.f;
            u16x4 pk;
            #pragma unroll
            for (int r = 0; r < 4; ++r) {
                float pe = keep[jt][r] ? __expf(v[jt][r] - mj) : 0.f;
                u16 pb = f2bf(pe);
                pk[r] = pb;
                ls += bf2f(pb);  // Z consistent with bf16-rounded alpha
            }
            zpart[jt] = zpart[jt] * scj + ls;
            *(u16x4*)&pT[jt * 16 + l15][w * 16 + quad * 4] = pk;
        }
        float hs[4];
        #pragma unroll
        for (int r = 0; r < 4; ++r) hs[r] = scale_s[mtile * 16 + quad * 4 + r];
        #pragma unroll
        for (int nt = 0; nt < 4; ++nt)
            #pragma unroll
            for (int r = 0; r < 4; ++r) H[nt][r] *= hs[r];
        __syncthreads();  // B3

        // phase B: H += P^T . z  (A[m=j][k=i] from pT, B[k=i][n=d] from bz)
        bf16x8 ap[2];
        #pragma unroll
        for (int ks = 0; ks < 2; ++ks)
            ap[ks] = *(const bf16x8*)&pT[mtile * 16 + l15][ks * 32 + quad * 8];
        #pragma unroll
        for (int ks = 0; ks < 2; ++ks)
            #pragma unroll
            for (int nt = 0; nt < 4; ++nt)
                H[nt] = __builtin_amdgcn_mfma_f32_16x16x32_bf16(ap[ks], bz[nt][ks], H[nt], 0, 0, 0);
    }

    // ---- epilogue: Z reduce, normalize, bias, elu, mean over j
    red[w * 4 + quad][l15] = zpart[0];
    red[w * 4 + quad][16 + l15] = zpart[1];
    __syncthreads();
    if (t < 32) {
        float s = 0.f;
        #pragma unroll
        for (int g = 0; g < 16; ++g) s += red[g][t];
        Zs[t] = 1.0f / s;  // self-loop guarantees s > 0
    }
    __syncthreads();

    float zi[4];
    #pragma unroll
    for (int r = 0; r < 4; ++r) zi[r] = Zs[mtile * 16 + quad * 4 + r];
    #pragma unroll
    for (int nt = 0; nt < 4; ++nt) {
        int d = (ngrp + nt) * 16 + l15;
        float bsv = bias[d];
        float a = 0.f;
        #pragma unroll
        for (int r = 0; r < 4; ++r) {
            float val = H[nt][r] * zi[r] + bsv;
            val = val > 0.f ? val : (__expf(val) - 1.f);
            a += val;
        }
        atomicAdd(&osum[d], a);
    }
    __syncthreads();
    if (t < 128) atomicAdd(&out[b * DD + t], osum[t] * (1.0f / NN));
}

// ---------------------------------------------------------------------------
extern "C" void kernel_launch(void* const* d_in, const int* in_sizes, int n_in,
                              void* d_out, int out_size, void* d_ws, size_t ws_size,
                              hipStream_t stream) {
    const float* E    = (const float*)d_in[0];
    const float* W    = (const float*)d_in[1];
    const float* al   = (const float*)d_in[2];
    const float* ar   = (const float*)d_in[3];
    const float* bias = (const float*)d_in[4];
    float* out = (float*)d_out;

    u16* Ebf = (u16*)d_ws;                                   // 8 MB
    u16* zTb = Ebf + (size_t)BATCH * NN * DD;                // 8 MB
    float* el  = (float*)(zTb + (size_t)BATCH * NN * DD);    // B*N
    float* er  = el + (size_t)BATCH * NN;                    // B*N
    float* thr = er + (size_t)BATCH * NN;                    // B

    hipMemsetAsync(d_out, 0, sizeof(float) * (size_t)out_size, stream);

    k_thresh<<<dim3(BATCH), dim3(1024), 0, stream>>>(E, thr);
    k_z<<<dim3(NN / 8, BATCH), dim3(128), 0, stream>>>(E, W, al, ar, Ebf, zTb, el, er);
    k_main<<<dim3(NN / 32, BATCH), dim3(256), 0, stream>>>(Ebf, zTb, el, er, thr, bias, out);
}

// Round 3
// 158.991 us; speedup vs baseline: 2.6970x; 1.0267x over previous
//
#include <hip/hip_runtime.h>
#include <math.h>

#define BATCH 64
#define NN 512
#define DD 128
#define SLOPE 0.2f

typedef unsigned short u16;
typedef short bf16x8 __attribute__((ext_vector_type(8)));
typedef u16 u16x4 __attribute__((ext_vector_type(4)));
typedef float f32x4 __attribute__((ext_vector_type(4)));

static __device__ __forceinline__ u16 f2bf(float x) {
    unsigned int u = __float_as_uint(x);
    unsigned int r = (u + 0x7fffu + ((u >> 16) & 1u)) >> 16;
    return (u16)r;
}
static __device__ __forceinline__ float bf2f(u16 h) {
    return __uint_as_float(((unsigned int)h) << 16);
}

// ---------------------------------------------------------------------------
// Kernel W: W^T split into bf16 hi/lo. WtHi/WtLo are [n][k] (transpose of W).
// ---------------------------------------------------------------------------
__global__ __launch_bounds__(256) void k_w(const float* __restrict__ W,
                                           u16* __restrict__ WtHi,
                                           u16* __restrict__ WtLo) {
    int t = threadIdx.x;
    #pragma unroll
    for (int it = 0; it < 64; ++it) {
        int idx = t + it * 256;
        int n = idx >> 7, k = idx & 127;
        float v = W[(size_t)k * DD + n];
        u16 h = f2bf(v);
        u16 l = f2bf(v - bf2f(h));
        WtHi[idx] = h;  // idx = n*128+k : coalesced write
        WtLo[idx] = l;
    }
}

// ---------------------------------------------------------------------------
// Kernel Z: split-bf16 MFMA z = E@W; writes Ebf (bf16 hi of E), zT (bf16
// z^T [B][D][N]), el/er (fp32, from fp32 accumulators), colsum atomics
// (for thresh identity: mean(E E^T) = ||colsum||^2 / N^2).
// Block = (64 nodes, b), 256 threads = 4 waves.
// ---------------------------------------------------------------------------
__global__ __launch_bounds__(256) void k_z(const float* __restrict__ E,
                                           const u16* __restrict__ WtHi,
                                           const u16* __restrict__ WtLo,
                                           const float* __restrict__ al,
                                           const float* __restrict__ ar,
                                           u16* __restrict__ Ebf,
                                           u16* __restrict__ zT,
                                           float* __restrict__ el,
                                           float* __restrict__ er,
                                           float* __restrict__ colsum) {
    int b = blockIdx.y;
    int n0 = blockIdx.x * 64;
    int t = threadIdx.x;
    int w = t >> 6;
    int lane = t & 63;
    int l15 = lane & 15;
    int quad = lane >> 4;

    __shared__ u16 ehi[64][136];   // +8 pad: b128 reads conflict-free
    __shared__ u16 elo[64][136];
    __shared__ float csr[8][128];
    __shared__ float als[128], ars[128];

    const float* Eb = E + ((size_t)b * NN + n0) * DD;
    if (t < 128) { als[t] = al[t]; ars[t] = ar[t]; }

    // ---- stage E -> hi/lo LDS + Ebf global + colsum partials
    {
        int c4 = t & 31;           // column group (4 floats)
        int r0 = t >> 5;           // row 0..7, +8 per iter
        float cp0 = 0.f, cp1 = 0.f, cp2 = 0.f, cp3 = 0.f;
        #pragma unroll
        for (int k = 0; k < 8; ++k) {
            int row = r0 + k * 8;
            float4 v = *(const float4*)&Eb[(size_t)row * DD + c4 * 4];
            cp0 += v.x; cp1 += v.y; cp2 += v.z; cp3 += v.w;
            u16x4 hv, lv;
            hv[0] = f2bf(v.x); lv[0] = f2bf(v.x - bf2f(hv[0]));
            hv[1] = f2bf(v.y); lv[1] = f2bf(v.y - bf2f(hv[1]));
            hv[2] = f2bf(v.z); lv[2] = f2bf(v.z - bf2f(hv[2]));
            hv[3] = f2bf(v.w); lv[3] = f2bf(v.w - bf2f(hv[3]));
            *(u16x4*)&ehi[row][c4 * 4] = hv;
            *(u16x4*)&elo[row][c4 * 4] = lv;
            *(u16x4*)&Ebf[((size_t)b * NN + n0 + row) * DD + c4 * 4] = hv;
        }
        csr[r0][c4 * 4 + 0] = cp0;
        csr[r0][c4 * 4 + 1] = cp1;
        csr[r0][c4 * 4 + 2] = cp2;
        csr[r0][c4 * 4 + 3] = cp3;
    }
    __syncthreads();
    if (t < 128) {
        float s = 0.f;
        #pragma unroll
        for (int g = 0; g < 8; ++g) s += csr[g][t];
        atomicAdd(&colsum[b * DD + t], s);
    }

    // ---- A-frags (hi/lo) for this wave's 16 rows
    bf16x8 ah[4], alo_f[4];
    #pragma unroll
    for (int ks = 0; ks < 4; ++ks) {
        ah[ks]    = *(const bf16x8*)&ehi[w * 16 + l15][ks * 32 + quad * 8];
        alo_f[ks] = *(const bf16x8*)&elo[w * 16 + l15][ks * 32 + quad * 8];
    }

    float elp[4] = {0.f, 0.f, 0.f, 0.f};
    float erp[4] = {0.f, 0.f, 0.f, 0.f};

    #pragma unroll 2
    for (int nt = 0; nt < 8; ++nt) {
        const u16* bh_p = WtHi + (size_t)(nt * 16 + l15) * DD + quad * 8;
        const u16* bl_p = WtLo + (size_t)(nt * 16 + l15) * DD + quad * 8;
        bf16x8 bh[4], bl[4];
        #pragma unroll
        for (int ks = 0; ks < 4; ++ks) {
            bh[ks] = *(const bf16x8*)(bh_p + ks * 32);
            bl[ks] = *(const bf16x8*)(bl_p + ks * 32);
        }
        f32x4 C = (f32x4){0.f, 0.f, 0.f, 0.f};
        #pragma unroll
        for (int ks = 0; ks < 4; ++ks) {
            C = __builtin_amdgcn_mfma_f32_16x16x32_bf16(ah[ks], bh[ks], C, 0, 0, 0);
            C = __builtin_amdgcn_mfma_f32_16x16x32_bf16(alo_f[ks], bh[ks], C, 0, 0, 0);
            C = __builtin_amdgcn_mfma_f32_16x16x32_bf16(ah[ks], bl[ks], C, 0, 0, 0);
        }
        // el/er partials (fp32 accumulators) + zT bf16 store
        float av = als[nt * 16 + l15], rv = ars[nt * 16 + l15];
        u16x4 zp;
        #pragma unroll
        for (int r = 0; r < 4; ++r) {
            elp[r] += C[r] * av;
            erp[r] += C[r] * rv;
            zp[r] = f2bf(C[r]);
        }
        *(u16x4*)&zT[((size_t)b * DD + nt * 16 + l15) * NN + n0 + w * 16 + quad * 4] = zp;
    }

    // ---- reduce el/er over the 16 lanes of each quad-group
    #pragma unroll
    for (int r = 0; r < 4; ++r) {
        float vl = elp[r], vr = erp[r];
        #pragma unroll
        for (int off = 8; off > 0; off >>= 1) {
            vl += __shfl_down(vl, off);
            vr += __shfl_down(vr, off);
        }
        if (l15 == 0) {
            int node = n0 + w * 16 + quad * 4 + r;
            el[b * NN + node] = vl;
            er[b * NN + node] = vr;
        }
    }
}

// ---------------------------------------------------------------------------
// Kernel main: masked GAT attention, max-free softmax, 1 barrier per chunk.
// Block = (b, 32 dst cols) via XCD-swizzled flat id; 256 threads = 4 waves.
// ---------------------------------------------------------------------------
__global__ __launch_bounds__(256) void k_main(const u16* __restrict__ Ebf,
                                              const u16* __restrict__ zT,
                                              const float* __restrict__ el,
                                              const float* __restrict__ er,
                                              const float* __restrict__ colsum,
                                              const float* __restrict__ bias,
                                              float* __restrict__ out) {
    int bid = blockIdx.x;
    // XCD swizzle: all 16 blocks of a batch share one XCD's L2
    int b = (bid & 7) * 8 + ((bid >> 3) >> 4);
    int j0 = ((bid >> 3) & 15) * 32;
    int t = threadIdx.x;
    int w = t >> 6;
    int lane = t & 63;
    int l15 = lane & 15;
    int quad = lane >> 4;
    int mtile = w & 1;
    int ngrp = (w >> 1) * 4;

    const u16* Eb = Ebf + (size_t)b * NN * DD;
    const u16* zTb = zT + (size_t)b * DD * NN;

    __shared__ u16 pT[2][32][72];   // P^T double-buffered, padded
    __shared__ float red[16][33];
    __shared__ float Zs[32];
    __shared__ float osum[128];
    __shared__ float tred[2];

    // persistent Ej B-frags
    bf16x8 bEj[2][4];
    #pragma unroll
    for (int jt = 0; jt < 2; ++jt)
        #pragma unroll
        for (int ks = 0; ks < 4; ++ks)
            bEj[jt][ks] = *(const bf16x8*)(Eb + (size_t)(j0 + jt * 16 + l15) * DD + ks * 32 + quad * 8);

    float er_v[2] = { er[b * NN + j0 + l15], er[b * NN + j0 + 16 + l15] };

    // thresh from colsum: ||colsum||^2 / N^2
    if (t < 128) {
        float c = colsum[b * DD + t];
        float v = c * c;
        #pragma unroll
        for (int off = 32; off > 0; off >>= 1) v += __shfl_down(v, off);
        if ((t & 63) == 0) tred[t >> 6] = v;
        osum[t] = 0.f;
    }

    f32x4 H[4];
    #pragma unroll
    for (int nt = 0; nt < 4; ++nt) H[nt] = (f32x4){0.f, 0.f, 0.f, 0.f};
    float zpart[2] = {0.f, 0.f};

    __syncthreads();
    float thr = (tred[0] + tred[1]) * (1.0f / ((float)NN * (float)NN));

    for (int c = 0; c < 8; ++c) {
        int i0 = c * 64;
        int ib = i0 + w * 16;

        // phase-B B-frags first (longest time to use)
        bf16x8 bz[4][2];
        #pragma unroll
        for (int nt = 0; nt < 4; ++nt)
            #pragma unroll
            for (int ks = 0; ks < 2; ++ks)
                bz[nt][ks] = *(const bf16x8*)(zTb + (size_t)((ngrp + nt) * 16 + l15) * NN + i0 + ks * 32 + quad * 8);

        // score A-frags
        bf16x8 aE[4];
        #pragma unroll
        for (int ks = 0; ks < 4; ++ks)
            aE[ks] = *(const bf16x8*)(Eb + (size_t)(ib + l15) * DD + ks * 32 + quad * 8);

        f32x4 S[2];
        S[0] = (f32x4){0.f, 0.f, 0.f, 0.f};
        S[1] = (f32x4){0.f, 0.f, 0.f, 0.f};
        #pragma unroll
        for (int ks = 0; ks < 4; ++ks) {
            S[0] = __builtin_amdgcn_mfma_f32_16x16x32_bf16(aE[ks], bEj[0][ks], S[0], 0, 0, 0);
            S[1] = __builtin_amdgcn_mfma_f32_16x16x32_bf16(aE[ks], bEj[1][ks], S[1], 0, 0, 0);
        }

        // mask + max-free exp -> pT, Z partials
        float4 el4 = *(const float4*)(el + b * NN + ib + quad * 4);
        float elv[4] = {el4.x, el4.y, el4.z, el4.w};
        #pragma unroll
        for (int jt = 0; jt < 2; ++jt) {
            float ls = 0.f;
            u16x4 pk;
            #pragma unroll
            for (int r = 0; r < 4; ++r) {
                int ig = ib + quad * 4 + r;
                int jg = j0 + jt * 16 + l15;
                float x = elv[r] + er_v[jt];
                float lg = x > 0.f ? x : SLOPE * x;
                bool keep = (S[jt][r] > thr) || (ig == jg);
                float pe = keep ? __expf(lg) : 0.f;
                u16 pb = f2bf(pe);
                pk[r] = pb;
                ls += bf2f(pb);
            }
            zpart[jt] += ls;
            *(u16x4*)&pT[c & 1][jt * 16 + l15][w * 16 + quad * 4] = pk;
        }
        __syncthreads();

        // phase B: H += P^T . z
        bf16x8 ap[2];
        #pragma unroll
        for (int ks = 0; ks < 2; ++ks)
            ap[ks] = *(const bf16x8*)&pT[c & 1][mtile * 16 + l15][ks * 32 + quad * 8];
        #pragma unroll
        for (int ks = 0; ks < 2; ++ks)
            #pragma unroll
            for (int nt = 0; nt < 4; ++nt)
                H[nt] = __builtin_amdgcn_mfma_f32_16x16x32_bf16(ap[ks], bz[nt][ks], H[nt], 0, 0, 0);
    }

    // ---- epilogue: Z reduce, normalize, bias, elu, mean over j
    red[w * 4 + quad][l15] = zpart[0];
    red[w * 4 + quad][16 + l15] = zpart[1];
    __syncthreads();
    if (t < 32) {
        float s = 0.f;
        #pragma unroll
        for (int g = 0; g < 16; ++g) s += red[g][t];
        Zs[t] = 1.0f / s;  // self-loop guarantees s > 0
    }
    __syncthreads();

    float zi[4];
    #pragma unroll
    for (int r = 0; r < 4; ++r) zi[r] = Zs[mtile * 16 + quad * 4 + r];
    #pragma unroll
    for (int nt = 0; nt < 4; ++nt) {
        int d = (ngrp + nt) * 16 + l15;
        float bsv = bias[d];
        float a = 0.f;
        #pragma unroll
        for (int r = 0; r < 4; ++r) {
            float val = H[nt][r] * zi[r] + bsv;
            val = val > 0.f ? val : (__expf(val) - 1.f);
            a += val;
        }
        atomicAdd(&osum[d], a);
    }
    __syncthreads();
    if (t < 128) atomicAdd(&out[b * DD + t], osum[t] * (1.0f / NN));
}

// ---------------------------------------------------------------------------
extern "C" void kernel_launch(void* const* d_in, const int* in_sizes, int n_in,
                              void* d_out, int out_size, void* d_ws, size_t ws_size,
                              hipStream_t stream) {
    const float* E    = (const float*)d_in[0];
    const float* W    = (const float*)d_in[1];
    const float* al   = (const float*)d_in[2];
    const float* ar   = (const float*)d_in[3];
    const float* bias = (const float*)d_in[4];
    float* out = (float*)d_out;

    u16* Ebf = (u16*)d_ws;                                     // 8 MB
    u16* zTb = Ebf + (size_t)BATCH * NN * DD;                  // 8 MB
    u16* WtHi = zTb + (size_t)BATCH * NN * DD;                 // 32 KB
    u16* WtLo = WtHi + (size_t)DD * DD;                        // 32 KB
    float* el  = (float*)(WtLo + (size_t)DD * DD);             // 128 KB
    float* er  = el + (size_t)BATCH * NN;                      // 128 KB
    float* colsum = er + (size_t)BATCH * NN;                   // 32 KB

    hipMemsetAsync(d_out, 0, sizeof(float) * (size_t)out_size, stream);
    hipMemsetAsync(colsum, 0, sizeof(float) * (size_t)BATCH * DD, stream);

    k_w<<<dim3(1), dim3(256), 0, stream>>>(W, WtHi, WtLo);
    k_z<<<dim3(NN / 64, BATCH), dim3(256), 0, stream>>>(E, WtHi, WtLo, al, ar,
                                                        Ebf, zTb, el, er, colsum);
    k_main<<<dim3(BATCH * NN / 32), dim3(256), 0, stream>>>(Ebf, zTb, el, er,
                                                            colsum, bias, out);
}